// Round 2
// baseline (882.821 us; speedup 1.0000x reference)
//
#include <hip/hip_runtime.h>
#include <hip/hip_bf16.h>
#include <stdint.h>

// TemporalAttention fused kernel for MI355X (gfx950).
// B=16, N=256, T=128, H=128, TD=32, NUM_NODES=256.
// R2: 512 threads / 8 waves per block (16 query rows per wave) -> 2 waves/SIMD
//     (was 1), merged Q/K/V GEMMs sharing one A-fragment read.

typedef __bf16 bf16;
typedef __bf16 bf16x4 __attribute__((ext_vector_type(4)));
typedef __bf16 bf16x8 __attribute__((ext_vector_type(8)));
typedef float  f32x4  __attribute__((ext_vector_type(4)));

#define MFMA16(a, b, c) __builtin_amdgcn_mfma_f32_16x16x32_bf16((a), (b), (c), 0, 0, 0)

__device__ __forceinline__ int allBytesNonzero(unsigned v) {
    return ((v - 0x01010101u) & ~v & 0x80808080u) == 0u;
}

__device__ __forceinline__ bf16x8 cvt8(const float* p) {
    float4 f0 = *reinterpret_cast<const float4*>(p);
    float4 f1 = *reinterpret_cast<const float4*>(p + 4);
    bf16x8 r;
    r[0] = (bf16)f0.x; r[1] = (bf16)f0.y; r[2] = (bf16)f0.z; r[3] = (bf16)f0.w;
    r[4] = (bf16)f1.x; r[5] = (bf16)f1.y; r[6] = (bf16)f1.z; r[7] = (bf16)f1.w;
    return r;
}

// ---- pre-kernel 1: transpose W1(=W_in[0:128]), Wq, Wk, Wv, Wo to bf16 [h][k] ----
__global__ void prep_weights(const float* __restrict__ W_in,
                             const float* __restrict__ Wq, const float* __restrict__ Wk,
                             const float* __restrict__ Wv, const float* __restrict__ Wo,
                             bf16* __restrict__ dst)
{
    int idx = blockIdx.x * 256 + threadIdx.x;
    if (idx >= 5 * 16384) return;
    int m = idx >> 14, r = idx & 16383;
    int h = r >> 7, k = r & 127;
    const float* src = (m == 0) ? W_in : (m == 1) ? Wq : (m == 2) ? Wk : (m == 3) ? Wv : Wo;
    dst[(m << 14) + h * 128 + k] = (bf16)src[k * 128 + h];  // dst[m][h][k] = W[k][h]
}

// ---- pre-kernel 2: npart[n][h] = E_node[nf[n]] @ W_in[256:384] (f32) ----
__global__ void prep_npart(const int* __restrict__ nf, const float* __restrict__ E_node,
                           const float* __restrict__ W_in, float* __restrict__ npart)
{
    int n = blockIdx.x, h = threadIdx.x;
    int node = nf[n];
    const float* e = E_node + node * 128;
    float acc = 0.f;
    for (int k = 0; k < 128; ++k) acc += e[k] * W_in[(256 + k) * 128 + h];
    npart[n * 128 + h] = acc;
}

// ---- pre-kernel 3: biasBT[b][t][h] = pe[t]@W1 + (ex[b,t]@W_t + b_t)@W2 + b_in (f32) ----
__global__ void prep_bias(const float* __restrict__ ex, const float* __restrict__ W_t,
                          const float* __restrict__ b_t, const float* __restrict__ W_in,
                          const float* __restrict__ b_in, float* __restrict__ biasBT)
{
    const int bt = blockIdx.x;          // b*128 + t
    const int t = bt & 127;
    const int h = threadIdx.x;
    __shared__ float te[128];
    float v = b_t[h];
    const float* exr = ex + (size_t)bt * 32;
    for (int d = 0; d < 32; ++d) v += exr[d] * W_t[d * 128 + h];
    te[h] = v;
    __syncthreads();
    float acc = b_in[h];
    const float ninv = -9.210340371976184f / 128.0f;   // -ln(10000)/H
    for (int j = 0; j < 64; ++j) {
        float div = expf((float)(2 * j) * ninv);
        float ang = (float)t * div;
        acc += sinf(ang) * W_in[(2 * j) * 128 + h] + cosf(ang) * W_in[(2 * j + 1) * 128 + h];
    }
    for (int k = 0; k < 128; ++k) acc += te[k] * W_in[(128 + k) * 128 + h];
    biasBT[(size_t)bt * 128 + h] = acc;
}

// ---- main fused kernel: 1 block per (b,n), 8 waves, wave w owns query rows [16w,16w+16) ----
// MFMA 16x16x32 layouts: A: row=lane&15, k=(lane>>4)*8+j;
// B: col=lane&15, k=(lane>>4)*8+j; C/D: col=lane&15, row=(lane>>4)*4+reg.
__global__ __launch_bounds__(512, 2) void fused_main(
    const float* __restrict__ xf, const unsigned char* __restrict__ mask,
    const bf16* __restrict__ wsW, const float* __restrict__ biasBT,
    const float* __restrict__ npart,
    const float* __restrict__ bq, const float* __restrict__ bk,
    const float* __restrict__ bv, const float* __restrict__ bo,
    float* __restrict__ out)
{
    const bf16* W1T = wsW;
    const bf16* WqT = wsW + 16384;
    const bf16* WkT = wsW + 32768;
    const bf16* WvT = wsW + 49152;
    const bf16* WoT = wsW + 65536;

    // stride 136 elems = 272 B = 17*16 B: b128 reads stay 16B-aligned, rows 4 banks apart.
    __shared__ bf16 sA[128][136];   // x[t][h]  -> later P[s][t]   (rows wave-private)
    __shared__ bf16 sK[128][136];   // k[t][h]
    __shared__ bf16 sV[128][136];   // vT[h][t]
    __shared__ bf16 sQ[128][136];   // q[s][h]  -> later rec[s][h] (rows wave-private)
    __shared__ float sTm[128];

    const int bn = blockIdx.x;
    const int b  = bn >> 8;
    const int n  = bn & 255;
    const int tid  = (int)threadIdx.x;
    const int w    = tid >> 6;      // 0..7
    const int lane = tid & 63;
    const int c = lane & 15;
    const int g = lane >> 4;
    const int s0 = w << 4;          // 16 rows per wave

    const f32x4 FZ = {0.f, 0.f, 0.f, 0.f};

    // ---- t_mask[t] = all(mask[b,n,t,:]) ; one thread per row reads 128 bytes ----
    if (tid < 128) {
        const uint4* mp = reinterpret_cast<const uint4*>(mask + ((size_t)bn * 128 + tid) * 128);
        int ok = 1;
        #pragma unroll
        for (int i = 0; i < 8; ++i) {
            uint4 u = mp[i];
            ok &= allBytesNonzero(u.x) & allBytesNonzero(u.y)
                & allBytesNonzero(u.z) & allBytesNonzero(u.w);
        }
        sTm[tid] = ok ? 1.0f : 0.0f;
    }

    // ---------- GEMM1: x = gelu(xf @ W1 + biasBT[b] + npart[n]) -> sA rows [s0,s0+16) ----------
    {
        f32x4 acc[8];
        #pragma unroll
        for (int ct = 0; ct < 8; ++ct) acc[ct] = FZ;

        const float* xfb = xf + (size_t)bn * (128 * 128);
        #pragma unroll
        for (int kk = 0; kk < 4; ++kk) {
            const int k0 = kk * 32 + g * 8;
            bf16x8 a0 = cvt8(xfb + (s0 + c) * 128 + k0);
            #pragma unroll
            for (int ct = 0; ct < 8; ++ct) {
                bf16x8 bw = *reinterpret_cast<const bf16x8*>(W1T + (ct * 16 + c) * 128 + k0);
                acc[ct] = MFMA16(a0, bw, acc[ct]);
            }
        }
        const float* biasRow = biasBT + (size_t)b * (128 * 128);
        const float* npRow   = npart + n * 128;
        #pragma unroll
        for (int ct = 0; ct < 8; ++ct) {
            const int h = ct * 16 + c;
            const float npv = npRow[h];
            #pragma unroll
            for (int r = 0; r < 4; ++r) {
                const int t = s0 + g * 4 + r;
                float v  = acc[ct][r] + biasRow[t * 128 + h] + npv;
                float ge = 0.5f * v * (1.0f + erff(v * 0.70710678118654752f));
                sA[t][h] = (bf16)ge;
            }
        }
    }

    // ---------- merged QKV: q,k,v = x @ W{q,k,v} + b ; one A-frag read feeds 3 MFMAs ----------
    {
        f32x4 aq[8], ak[8], av[8];
        #pragma unroll
        for (int ct = 0; ct < 8; ++ct) { aq[ct] = FZ; ak[ct] = FZ; av[ct] = FZ; }
        #pragma unroll
        for (int kk = 0; kk < 4; ++kk) {
            const int k0 = kk * 32 + g * 8;
            bf16x8 a0 = *reinterpret_cast<const bf16x8*>(&sA[s0 + c][k0]);
            #pragma unroll
            for (int ct = 0; ct < 8; ++ct) {
                const int woff = (ct * 16 + c) * 128 + k0;
                bf16x8 wq = *reinterpret_cast<const bf16x8*>(WqT + woff);
                bf16x8 wk = *reinterpret_cast<const bf16x8*>(WkT + woff);
                bf16x8 wv = *reinterpret_cast<const bf16x8*>(WvT + woff);
                aq[ct] = MFMA16(a0, wq, aq[ct]);
                ak[ct] = MFMA16(a0, wk, ak[ct]);
                av[ct] = MFMA16(a0, wv, av[ct]);
            }
        }
        #pragma unroll
        for (int ct = 0; ct < 8; ++ct) {
            const int h = ct * 16 + c;
            const float bqv = bq[h];
            const float bkv = bk[h];
            const float bvv = bv[h];
            #pragma unroll
            for (int r = 0; r < 4; ++r) {
                const int t = s0 + g * 4 + r;
                sQ[t][h] = (bf16)(aq[ct][r] + bqv);
                sK[t][h] = (bf16)(ak[ct][r] + bkv);
            }
            bf16x4 pk;
            #pragma unroll
            for (int r = 0; r < 4; ++r) pk[r] = (bf16)(av[ct][r] + bvv);
            *reinterpret_cast<bf16x4*>(&sV[h][s0 + g * 4]) = pk;
        }
    }

    __syncthreads();   // the only block-wide barrier: publishes sK, sV, sTm

    const float rs = 0.08838834764831845f;  // 1/sqrt(128)
    float l0 = 1.f;

    // ---------- scoresT[t][s] = K·Qᵀ ; softmax over t ; P -> sA[s][t] ----------
    {
        f32x4 sc[8];
        #pragma unroll
        for (int rt = 0; rt < 8; ++rt) sc[rt] = FZ;
        #pragma unroll
        for (int kk = 0; kk < 4; ++kk) {
            const int k0 = kk * 32 + g * 8;
            bf16x8 q0 = *reinterpret_cast<const bf16x8*>(&sQ[s0 + c][k0]);
            #pragma unroll
            for (int rt = 0; rt < 8; ++rt) {
                bf16x8 akf = *reinterpret_cast<const bf16x8*>(&sK[rt * 16 + c][k0]);
                sc[rt] = MFMA16(akf, q0, sc[rt]);
            }
        }
        float m = -3.0e38f;
        #pragma unroll
        for (int rt = 0; rt < 8; ++rt)
            #pragma unroll
            for (int r = 0; r < 4; ++r) m = fmaxf(m, sc[rt][r]);
        m = fmaxf(m, __shfl_xor(m, 16));
        m = fmaxf(m, __shfl_xor(m, 32));
        float ls = 0.f, wsum = 0.f;
        #pragma unroll
        for (int rt = 0; rt < 8; ++rt) {
            #pragma unroll
            for (int r = 0; r < 4; ++r) {
                float p = __expf((sc[rt][r] - m) * rs);
                sc[rt][r] = p;
                ls += p;
                wsum += p * sTm[rt * 16 + g * 4 + r];
            }
        }
        ls   += __shfl_xor(ls, 16);   ls   += __shfl_xor(ls, 32);
        wsum += __shfl_xor(wsum, 16); wsum += __shfl_xor(wsum, 32);
        l0 = ls;
        if (g == 0)
            out[(size_t)67108864 + (size_t)bn * 128 + s0 + c] = 1.0f - wsum / ls;
        // store unnormalized P (divide by l after PV)
        #pragma unroll
        for (int rt = 0; rt < 8; ++rt) {
            bf16x4 pk;
            #pragma unroll
            for (int r = 0; r < 4; ++r) pk[r] = (bf16)sc[rt][r];
            *reinterpret_cast<bf16x4*>(&sA[s0 + c][rt * 16 + g * 4]) = pk;
        }
    }

    // ---------- recT[h][s] = Vᵀ·P ; normalize ; rec -> sQ[s][h] ----------
    {
        f32x4 rc[8];
        #pragma unroll
        for (int rt = 0; rt < 8; ++rt) rc[rt] = FZ;
        #pragma unroll
        for (int kk = 0; kk < 4; ++kk) {
            const int k0 = kk * 32 + g * 8;
            bf16x8 p0 = *reinterpret_cast<const bf16x8*>(&sA[s0 + c][k0]);
            #pragma unroll
            for (int rt = 0; rt < 8; ++rt) {
                bf16x8 avf = *reinterpret_cast<const bf16x8*>(&sV[rt * 16 + c][k0]);
                rc[rt] = MFMA16(avf, p0, rc[rt]);
            }
        }
        const float inv0 = 1.0f / l0;
        #pragma unroll
        for (int rt = 0; rt < 8; ++rt) {
            bf16x4 pk0;
            #pragma unroll
            for (int r = 0; r < 4; ++r) pk0[r] = (bf16)(rc[rt][r] * inv0);
            *reinterpret_cast<bf16x4*>(&sQ[s0 + c][rt * 16 + g * 4]) = pk0;
        }
    }

    // ---------- outT[ho][s] = Woᵀ·recᵀ + bo ; store f32 ----------
    {
        f32x4 oc[8];
        #pragma unroll
        for (int rt = 0; rt < 8; ++rt) oc[rt] = FZ;
        #pragma unroll
        for (int kk = 0; kk < 4; ++kk) {
            const int k0 = kk * 32 + g * 8;
            bf16x8 r0 = *reinterpret_cast<const bf16x8*>(&sQ[s0 + c][k0]);
            #pragma unroll
            for (int rt = 0; rt < 8; ++rt) {
                bf16x8 aw = *reinterpret_cast<const bf16x8*>(WoT + (rt * 16 + c) * 128 + k0);
                oc[rt] = MFMA16(aw, r0, oc[rt]);
            }
        }
        float* outb = out + (size_t)bn * (128 * 128);
        const int s = s0 + c;
        #pragma unroll
        for (int rt = 0; rt < 8; ++rt) {
            const int ho0 = rt * 16 + g * 4;
            const float4 bo4 = *reinterpret_cast<const float4*>(bo + ho0);
            float4 v;
            v.x = oc[rt][0] + bo4.x;
            v.y = oc[rt][1] + bo4.y;
            v.z = oc[rt][2] + bo4.z;
            v.w = oc[rt][3] + bo4.w;
            *reinterpret_cast<float4*>(outb + s * 128 + ho0) = v;
        }
    }
}

extern "C" void kernel_launch(void* const* d_in, const int* in_sizes, int n_in,
                              void* d_out, int out_size, void* d_ws, size_t ws_size,
                              hipStream_t stream)
{
    (void)in_sizes; (void)n_in; (void)out_size; (void)ws_size;
    const float* xf     = (const float*)d_in[0];
    const float* ex     = (const float*)d_in[1];
    const int*   nf     = (const int*)d_in[2];
    const unsigned char* mask = (const unsigned char*)d_in[3];
    const float* W_in   = (const float*)d_in[4];
    const float* b_in   = (const float*)d_in[5];
    const float* W_t    = (const float*)d_in[6];
    const float* b_t    = (const float*)d_in[7];
    const float* E_node = (const float*)d_in[8];
    const float* W_q    = (const float*)d_in[9];
    const float* b_q    = (const float*)d_in[10];
    const float* W_k    = (const float*)d_in[11];
    const float* b_k    = (const float*)d_in[12];
    const float* W_v    = (const float*)d_in[13];
    const float* b_v    = (const float*)d_in[14];
    const float* W_o    = (const float*)d_in[15];
    const float* b_o    = (const float*)d_in[16];
    float* out = (float*)d_out;

    // ws layout: [0, 163840) 5x bf16 128x128 transposed weights;
    //            [163840, 1212416) biasBT f32 [16][128][128];
    //            [1212416, 1343488) npart f32 [256][128].
    bf16*  wsW    = (bf16*)d_ws;
    float* biasBT = (float*)((char*)d_ws + 163840);
    float* npart  = (float*)((char*)d_ws + 163840 + 1048576);

    prep_weights<<<320, 256, 0, stream>>>(W_in, W_q, W_k, W_v, W_o, wsW);
    prep_npart<<<256, 128, 0, stream>>>(nf, E_node, W_in, npart);
    prep_bias<<<2048, 128, 0, stream>>>(ex, W_t, b_t, W_in, b_in, biasBT);
    fused_main<<<4096, 512, 0, stream>>>(xf, mask, wsW, biasBT, npart,
                                         b_q, b_k, b_v, b_o, out);
}

// Round 3
// 754.505 us; speedup vs baseline: 1.1701x; 1.1701x over previous
//
#include <hip/hip_runtime.h>
#include <hip/hip_bf16.h>
#include <stdint.h>

// TemporalAttention fused kernel for MI355X (gfx950).
// B=16, N=256, T=128, H=128, TD=32, NUM_NODES=256.
// R3: LDS 140KB->70KB (2 buffers: sX serves X->Q->P->rec, sKV serves K->V)
//     => 2 independent blocks/CU, 4 waves/SIMD. De-merged QKV loops, V held
//     packed bf16 in regs across scores. biasBT transposed for float4 loads.

typedef __bf16 bf16;
typedef __bf16 bf16x4 __attribute__((ext_vector_type(4)));
typedef __bf16 bf16x8 __attribute__((ext_vector_type(8)));
typedef float  f32x4  __attribute__((ext_vector_type(4)));

#define MFMA16(a, b, c) __builtin_amdgcn_mfma_f32_16x16x32_bf16((a), (b), (c), 0, 0, 0)

__device__ __forceinline__ int allBytesNonzero(unsigned v) {
    return ((v - 0x01010101u) & ~v & 0x80808080u) == 0u;
}

__device__ __forceinline__ bf16x8 cvt8(const float* p) {
    float4 f0 = *reinterpret_cast<const float4*>(p);
    float4 f1 = *reinterpret_cast<const float4*>(p + 4);
    bf16x8 r;
    r[0] = (bf16)f0.x; r[1] = (bf16)f0.y; r[2] = (bf16)f0.z; r[3] = (bf16)f0.w;
    r[4] = (bf16)f1.x; r[5] = (bf16)f1.y; r[6] = (bf16)f1.z; r[7] = (bf16)f1.w;
    return r;
}

// ---- pre-kernel 1: transpose W1(=W_in[0:128]), Wq, Wk, Wv, Wo to bf16 [h][k] ----
__global__ void prep_weights(const float* __restrict__ W_in,
                             const float* __restrict__ Wq, const float* __restrict__ Wk,
                             const float* __restrict__ Wv, const float* __restrict__ Wo,
                             bf16* __restrict__ dst)
{
    int idx = blockIdx.x * 256 + threadIdx.x;
    if (idx >= 5 * 16384) return;
    int m = idx >> 14, r = idx & 16383;
    int h = r >> 7, k = r & 127;
    const float* src = (m == 0) ? W_in : (m == 1) ? Wq : (m == 2) ? Wk : (m == 3) ? Wv : Wo;
    dst[(m << 14) + h * 128 + k] = (bf16)src[k * 128 + h];  // dst[m][h][k] = W[k][h]
}

// ---- pre-kernel 2: npart[n][h] = E_node[nf[n]] @ W_in[256:384] (f32) ----
__global__ void prep_npart(const int* __restrict__ nf, const float* __restrict__ E_node,
                           const float* __restrict__ W_in, float* __restrict__ npart)
{
    int n = blockIdx.x, h = threadIdx.x;
    int node = nf[n];
    const float* e = E_node + node * 128;
    float acc = 0.f;
    for (int k = 0; k < 128; ++k) acc += e[k] * W_in[(256 + k) * 128 + h];
    npart[n * 128 + h] = acc;
}

// ---- pre-kernel 3: biasT[b][h][t] = (pe[t]@W1 + (ex[b,t]@W_t + b_t)@W2 + b_in)[h] ----
// NOTE: stored TRANSPOSED (t fastest) so the main-kernel epilogue loads float4 over t.
__global__ void prep_bias(const float* __restrict__ ex, const float* __restrict__ W_t,
                          const float* __restrict__ b_t, const float* __restrict__ W_in,
                          const float* __restrict__ b_in, float* __restrict__ biasT)
{
    const int bt = blockIdx.x;          // b*128 + t
    const int b = bt >> 7;
    const int t = bt & 127;
    const int h = threadIdx.x;
    __shared__ float te[128];
    float v = b_t[h];
    const float* exr = ex + (size_t)bt * 32;
    for (int d = 0; d < 32; ++d) v += exr[d] * W_t[d * 128 + h];
    te[h] = v;
    __syncthreads();
    float acc = b_in[h];
    const float ninv = -9.210340371976184f / 128.0f;   // -ln(10000)/H
    for (int j = 0; j < 64; ++j) {
        float div = expf((float)(2 * j) * ninv);
        float ang = (float)t * div;
        acc += sinf(ang) * W_in[(2 * j) * 128 + h] + cosf(ang) * W_in[(2 * j + 1) * 128 + h];
    }
    for (int k = 0; k < 128; ++k) acc += te[k] * W_in[(128 + k) * 128 + h];
    biasT[(size_t)b * 16384 + h * 128 + t] = acc;
}

// ---- main fused kernel: 1 block per (b,n), 8 waves, wave w owns rows [16w,16w+16) ----
// MFMA 16x16x32 layouts: A: row=lane&15, k=(lane>>4)*8+j;
// B: col=lane&15, k=(lane>>4)*8+j; C/D: col(n)=lane&15, row(m)=(lane>>4)*4+reg.
__global__ __launch_bounds__(512, 4) void fused_main(
    const float* __restrict__ xf, const unsigned char* __restrict__ mask,
    const bf16* __restrict__ wsW, const float* __restrict__ biasT,
    const float* __restrict__ npart,
    const float* __restrict__ bq, const float* __restrict__ bk,
    const float* __restrict__ bv, const float* __restrict__ bo,
    float* __restrict__ out)
{
    const bf16* W1T = wsW;
    const bf16* WqT = wsW + 16384;
    const bf16* WkT = wsW + 32768;
    const bf16* WvT = wsW + 49152;
    const bf16* WoT = wsW + 65536;

    // stride 136 elems = 272 B = 17*16 B: b128 reads stay 16B-aligned.
    __shared__ bf16 sX[128][136];    // X -> Q -> P -> rec (wave-private row transitions)
    __shared__ bf16 sKV[128][136];   // K[t][h] -> V^T[h][t] (barrier-guarded swap)
    __shared__ float sTm[128];

    const int bn = blockIdx.x;
    const int b  = bn >> 8;
    const int n  = bn & 255;
    const int tid  = (int)threadIdx.x;
    const int w    = tid >> 6;      // 0..7
    const int lane = tid & 63;
    const int c = lane & 15;
    const int g = lane >> 4;
    const int s0 = w << 4;          // 16 rows per wave

    const f32x4 FZ = {0.f, 0.f, 0.f, 0.f};

    // ---- t_mask[t] = all(mask[b,n,t,:]) ----
    if (tid < 128) {
        const uint4* mp = reinterpret_cast<const uint4*>(mask + ((size_t)bn * 128 + tid) * 128);
        int ok = 1;
        #pragma unroll
        for (int i = 0; i < 8; ++i) {
            uint4 u = mp[i];
            ok &= allBytesNonzero(u.x) & allBytesNonzero(u.y)
                & allBytesNonzero(u.z) & allBytesNonzero(u.w);
        }
        sTm[tid] = ok ? 1.0f : 0.0f;
    }

    // ---------- GEMM1: x = gelu(xf @ W1 + biasT[b] + npart[n]) -> sX rows [s0,s0+16) ----------
    {
        f32x4 acc[8];
        #pragma unroll
        for (int ct = 0; ct < 8; ++ct) acc[ct] = FZ;

        const float* xfb = xf + (size_t)bn * (128 * 128);
        #pragma unroll
        for (int kk = 0; kk < 4; ++kk) {
            const int k0 = kk * 32 + g * 8;
            bf16x8 a0 = cvt8(xfb + (s0 + c) * 128 + k0);
            #pragma unroll
            for (int ct = 0; ct < 8; ++ct) {
                bf16x8 bw = *reinterpret_cast<const bf16x8*>(W1T + (ct * 16 + c) * 128 + k0);
                acc[ct] = MFMA16(a0, bw, acc[ct]);
            }
        }
        const float* biasB = biasT + (size_t)b * 16384;
        const float* npRow = npart + n * 128;
        #pragma unroll
        for (int ct = 0; ct < 8; ++ct) {
            const int h = ct * 16 + c;
            const float npv = npRow[h];
            const float4 bb = *reinterpret_cast<const float4*>(biasB + h * 128 + s0 + g * 4);
            const float bbr[4] = {bb.x, bb.y, bb.z, bb.w};
            #pragma unroll
            for (int r = 0; r < 4; ++r) {
                const int t = s0 + g * 4 + r;
                float v  = acc[ct][r] + bbr[r] + npv;
                float ge = 0.5f * v * (1.0f + erff(v * 0.70710678118654752f));
                sX[t][h] = (bf16)ge;
            }
        }
    }

    // ---------- QKV: three k-loops sharing sX; K -> sKV now, V packed to regs, Q -> sX last ----
    f32x4 aq[8];
    bf16x4 vpk[8];                   // V held packed bf16 across the scores phase (16 VGPRs)
    {
        #pragma unroll
        for (int ct = 0; ct < 8; ++ct) aq[ct] = FZ;
        #pragma unroll
        for (int kk = 0; kk < 4; ++kk) {
            const int k0 = kk * 32 + g * 8;
            bf16x8 a0 = *reinterpret_cast<const bf16x8*>(&sX[s0 + c][k0]);
            #pragma unroll
            for (int ct = 0; ct < 8; ++ct) {
                bf16x8 bw = *reinterpret_cast<const bf16x8*>(WqT + (ct * 16 + c) * 128 + k0);
                aq[ct] = MFMA16(a0, bw, aq[ct]);
            }
        }
    }
    {
        f32x4 ak[8];
        #pragma unroll
        for (int ct = 0; ct < 8; ++ct) ak[ct] = FZ;
        #pragma unroll
        for (int kk = 0; kk < 4; ++kk) {
            const int k0 = kk * 32 + g * 8;
            bf16x8 a0 = *reinterpret_cast<const bf16x8*>(&sX[s0 + c][k0]);
            #pragma unroll
            for (int ct = 0; ct < 8; ++ct) {
                bf16x8 bw = *reinterpret_cast<const bf16x8*>(WkT + (ct * 16 + c) * 128 + k0);
                ak[ct] = MFMA16(a0, bw, ak[ct]);
            }
        }
        #pragma unroll
        for (int ct = 0; ct < 8; ++ct) {
            const int h = ct * 16 + c;
            const float bkv = bk[h];
            #pragma unroll
            for (int r = 0; r < 4; ++r)
                sKV[s0 + g * 4 + r][h] = (bf16)(ak[ct][r] + bkv);
        }
    }
    {
        f32x4 av[8];
        #pragma unroll
        for (int ct = 0; ct < 8; ++ct) av[ct] = FZ;
        #pragma unroll
        for (int kk = 0; kk < 4; ++kk) {
            const int k0 = kk * 32 + g * 8;
            bf16x8 a0 = *reinterpret_cast<const bf16x8*>(&sX[s0 + c][k0]);
            #pragma unroll
            for (int ct = 0; ct < 8; ++ct) {
                bf16x8 bw = *reinterpret_cast<const bf16x8*>(WvT + (ct * 16 + c) * 128 + k0);
                av[ct] = MFMA16(a0, bw, av[ct]);
            }
        }
        #pragma unroll
        for (int ct = 0; ct < 8; ++ct) {
            const float bvv = bv[ct * 16 + c];
            #pragma unroll
            for (int r = 0; r < 4; ++r) vpk[ct][r] = (bf16)(av[ct][r] + bvv);
        }
    }
    // Q epilogue: all sX(X) reads done -> overwrite wave rows with Q
    {
        #pragma unroll
        for (int ct = 0; ct < 8; ++ct) {
            const int h = ct * 16 + c;
            const float bqv = bq[h];
            #pragma unroll
            for (int r = 0; r < 4; ++r)
                sX[s0 + g * 4 + r][h] = (bf16)(aq[ct][r] + bqv);
        }
    }

    __syncthreads();   // #1: publishes sKV=K, sTm (Q rows are wave-private)

    const float rs = 0.08838834764831845f;  // 1/sqrt(128)
    float l0 = 1.f;

    // ---------- scoresT[t][s] = K·Qᵀ ; softmax over t ; P -> sX[s][t] ----------
    {
        f32x4 sc[8];
        #pragma unroll
        for (int rt = 0; rt < 8; ++rt) sc[rt] = FZ;
        #pragma unroll
        for (int kk = 0; kk < 4; ++kk) {
            const int k0 = kk * 32 + g * 8;
            bf16x8 q0 = *reinterpret_cast<const bf16x8*>(&sX[s0 + c][k0]);
            #pragma unroll
            for (int rt = 0; rt < 8; ++rt) {
                bf16x8 akf = *reinterpret_cast<const bf16x8*>(&sKV[rt * 16 + c][k0]);
                sc[rt] = MFMA16(akf, q0, sc[rt]);
            }
        }
        float m = -3.0e38f;
        #pragma unroll
        for (int rt = 0; rt < 8; ++rt)
            #pragma unroll
            for (int r = 0; r < 4; ++r) m = fmaxf(m, sc[rt][r]);
        m = fmaxf(m, __shfl_xor(m, 16));
        m = fmaxf(m, __shfl_xor(m, 32));
        float ls = 0.f, wsum = 0.f;
        #pragma unroll
        for (int rt = 0; rt < 8; ++rt) {
            #pragma unroll
            for (int r = 0; r < 4; ++r) {
                float p = __expf((sc[rt][r] - m) * rs);
                sc[rt][r] = p;
                ls += p;
                wsum += p * sTm[rt * 16 + g * 4 + r];
            }
        }
        ls   += __shfl_xor(ls, 16);   ls   += __shfl_xor(ls, 32);
        wsum += __shfl_xor(wsum, 16); wsum += __shfl_xor(wsum, 32);
        l0 = ls;
        if (g == 0)
            out[(size_t)67108864 + (size_t)bn * 128 + s0 + c] = 1.0f - wsum / ls;
        // store unnormalized P over Q (wave-private rows)
        #pragma unroll
        for (int rt = 0; rt < 8; ++rt) {
            bf16x4 pk;
            #pragma unroll
            for (int r = 0; r < 4; ++r) pk[r] = (bf16)sc[rt][r];
            *reinterpret_cast<bf16x4*>(&sX[s0 + c][rt * 16 + g * 4]) = pk;
        }
    }

    __syncthreads();   // #2: all waves done reading sKV(K)

    // ---------- V (held in regs) -> sKV as V^T[h][t] ----------
    {
        #pragma unroll
        for (int ct = 0; ct < 8; ++ct)
            *reinterpret_cast<bf16x4*>(&sKV[ct * 16 + c][s0 + g * 4]) = vpk[ct];
    }

    __syncthreads();   // #3: publishes sKV=V^T

    // ---------- recT[h][s] = Vᵀ·P ; normalize ; rec -> sX[s][h] ----------
    {
        f32x4 rc[8];
        #pragma unroll
        for (int rt = 0; rt < 8; ++rt) rc[rt] = FZ;
        #pragma unroll
        for (int kk = 0; kk < 4; ++kk) {
            const int k0 = kk * 32 + g * 8;
            bf16x8 p0 = *reinterpret_cast<const bf16x8*>(&sX[s0 + c][k0]);
            #pragma unroll
            for (int rt = 0; rt < 8; ++rt) {
                bf16x8 avf = *reinterpret_cast<const bf16x8*>(&sKV[rt * 16 + c][k0]);
                rc[rt] = MFMA16(avf, p0, rc[rt]);
            }
        }
        const float inv0 = 1.0f / l0;
        #pragma unroll
        for (int rt = 0; rt < 8; ++rt) {
            bf16x4 pk0;
            #pragma unroll
            for (int r = 0; r < 4; ++r) pk0[r] = (bf16)(rc[rt][r] * inv0);
            *reinterpret_cast<bf16x4*>(&sX[s0 + c][rt * 16 + g * 4]) = pk0;
        }
    }

    // ---------- outT[ho][s] = Woᵀ·recᵀ + bo ; store f32 ----------
    {
        f32x4 oc[8];
        #pragma unroll
        for (int rt = 0; rt < 8; ++rt) oc[rt] = FZ;
        #pragma unroll
        for (int kk = 0; kk < 4; ++kk) {
            const int k0 = kk * 32 + g * 8;
            bf16x8 r0 = *reinterpret_cast<const bf16x8*>(&sX[s0 + c][k0]);
            #pragma unroll
            for (int rt = 0; rt < 8; ++rt) {
                bf16x8 aw = *reinterpret_cast<const bf16x8*>(WoT + (rt * 16 + c) * 128 + k0);
                oc[rt] = MFMA16(aw, r0, oc[rt]);
            }
        }
        float* outb = out + (size_t)bn * (128 * 128);
        const int s = s0 + c;
        #pragma unroll
        for (int rt = 0; rt < 8; ++rt) {
            const int ho0 = rt * 16 + g * 4;
            const float4 bo4 = *reinterpret_cast<const float4*>(bo + ho0);
            float4 v;
            v.x = oc[rt][0] + bo4.x;
            v.y = oc[rt][1] + bo4.y;
            v.z = oc[rt][2] + bo4.z;
            v.w = oc[rt][3] + bo4.w;
            *reinterpret_cast<float4*>(outb + s * 128 + ho0) = v;
        }
    }
}

extern "C" void kernel_launch(void* const* d_in, const int* in_sizes, int n_in,
                              void* d_out, int out_size, void* d_ws, size_t ws_size,
                              hipStream_t stream)
{
    (void)in_sizes; (void)n_in; (void)out_size; (void)ws_size;
    const float* xf     = (const float*)d_in[0];
    const float* ex     = (const float*)d_in[1];
    const int*   nf     = (const int*)d_in[2];
    const unsigned char* mask = (const unsigned char*)d_in[3];
    const float* W_in   = (const float*)d_in[4];
    const float* b_in   = (const float*)d_in[5];
    const float* W_t    = (const float*)d_in[6];
    const float* b_t    = (const float*)d_in[7];
    const float* E_node = (const float*)d_in[8];
    const float* W_q    = (const float*)d_in[9];
    const float* b_q    = (const float*)d_in[10];
    const float* W_k    = (const float*)d_in[11];
    const float* b_k    = (const float*)d_in[12];
    const float* W_v    = (const float*)d_in[13];
    const float* b_v    = (const float*)d_in[14];
    const float* W_o    = (const float*)d_in[15];
    const float* b_o    = (const float*)d_in[16];
    float* out = (float*)d_out;

    // ws layout: [0, 163840) 5x bf16 128x128 transposed weights;
    //            [163840, 1212416) biasT f32 [16][128][128] (t fastest);
    //            [1212416, 1343488) npart f32 [256][128].
    bf16*  wsW    = (bf16*)d_ws;
    float* biasT  = (float*)((char*)d_ws + 163840);
    float* npart  = (float*)((char*)d_ws + 163840 + 1048576);

    prep_weights<<<320, 256, 0, stream>>>(W_in, W_q, W_k, W_v, W_o, wsW);
    prep_npart<<<256, 128, 0, stream>>>(nf, E_node, W_in, npart);
    prep_bias<<<2048, 128, 0, stream>>>(ex, W_t, b_t, W_in, b_in, biasT);
    fused_main<<<4096, 512, 0, stream>>>(xf, mask, wsW, biasT, npart,
                                         b_q, b_k, b_v, b_o, out);
}